// Round 1
// baseline (455.723 us; speedup 1.0000x reference)
//
#include <hip/hip_runtime.h>
#include <hip/hip_bf16.h>

// KGE graph encoder, pruned to the backward cone of the 64 CLS nodes.
// R2: block-aggregated frontier scans (LDS buffer + one global atomic per
// flush); S1-sized zeroing; 8-node-tiled feat0 to amortize W_ent reads.
// R3: CSR-bucket layer-1 edges by S1 dst, then fully fused per-node layer
// kernels (score+softmax+message+normalize+project in registers). Removes
// ~2.5M scattered global atomicAdds (h1acc/den1/den2/out2) and the ex1
// round-trip; 15 -> 13 launches.

#define NN   50000      // N_NODES
#define NE   800000     // N_EDGES
#define NR   500        // N_REL
#define HH   8          // heads
#define DD   16         // per-head dim
#define HIDD 128        // HID == IN
#define BB   64         // batch (CLS nodes)

#define MAXE2 16384     // cap on |{e : dst in S2}|   (expect ~1K)
#define MAXS1 16448     // cap on |S1|                (expect ~1.1K)
#define MAXE1 262144    // cap on |{e : dst in S1}|   (expect ~18K)
#define MAXS0 50000     // node set, can't exceed NN  (expect ~19K)

// counters: [0]=cntS1 [1]=cntS0 [2]=cntE2 [3]=cntE1

__global__ void k_init(int* slot2, int* slot1, int* slot0, int* counters) {
    int i = blockIdx.x * blockDim.x + threadIdx.x;
    int stride = gridDim.x * blockDim.x;
    for (int n = i; n < NN; n += stride) { slot2[n] = -1; slot1[n] = -1; slot0[n] = -1; }
    if (i < 8) counters[i] = 0;
}

__global__ void k_seed(const int* goffs, int* slot2, int* slot1, int* nodesS1,
                       int* counters) {
    int i = threadIdx.x;
    if (i < BB) {
        int n = goffs[i];
        slot2[n] = i;        // graph index
        slot1[n] = -2;       // member of S1, slot assigned in k_finS1
        nodesS1[i] = n;
    }
    if (i == 0) counters[0] = BB;
}

// Generic frontier scan: edges whose dst is in slotHit (>=0) are appended to
// elist; their src nodes are CAS-claimed in slotNew and appended to nodes.
// All list appends are block-aggregated in LDS; one global atomicAdd per
// flush (instead of one per hit -> kills cross-XCD same-line serialization).
#define EBUF 1024
#define NBUF 512
__global__ void k_scan(const int* __restrict__ src, const int* __restrict__ dst,
                       const int* __restrict__ slotHit, int* __restrict__ slotNew,
                       int* elist, int elistCap, int* nodes, int nodesCap,
                       int* counters, int cntE, int cntN) {
    __shared__ int lE[EBUF];
    __shared__ int lN[NBUF];
    __shared__ int cEsh, cNsh, baseE, baseN;
    if (threadIdx.x == 0) { cEsh = 0; cNsh = 0; }
    __syncthreads();
    int per = (NE + gridDim.x - 1) / gridDim.x;
    int lo = blockIdx.x * per;
    int hi = lo + per; if (hi > NE) hi = NE;
    for (int base = lo; base < hi; base += blockDim.x) {
        int e = base + threadIdx.x;
        if (e < hi) {
            int d = dst[e];
            if (slotHit[d] >= 0) {
                int pos = atomicAdd(&cEsh, 1);   // LDS atomic: cheap
                lE[pos] = e;                     // bounded: flush threshold guarantees pos < EBUF
                int s = src[e];
                int old = atomicCAS(&slotNew[s], -1, -2);  // scattered, fine
                if (old == -1) {
                    int p2 = atomicAdd(&cNsh, 1);
                    lN[p2] = s;
                }
            }
        }
        __syncthreads();
        if (cEsh >= EBUF - 256 || cNsh >= NBUF - 256) {
            int nE = cEsh, nN = cNsh;
            if (threadIdx.x == 0) {
                baseE = atomicAdd(&counters[cntE], nE);
                baseN = atomicAdd(&counters[cntN], nN);
            }
            __syncthreads();
            for (int i = threadIdx.x; i < nE; i += blockDim.x) {
                int g = baseE + i; if (g < elistCap) elist[g] = lE[i];
            }
            for (int i = threadIdx.x; i < nN; i += blockDim.x) {
                int g = baseN + i; if (g < nodesCap) nodes[g] = lN[i];
            }
            __syncthreads();
            if (threadIdx.x == 0) { cEsh = 0; cNsh = 0; }
        }
        __syncthreads();
    }
    int nE = cEsh, nN = cNsh;
    if (threadIdx.x == 0) {
        baseE = atomicAdd(&counters[cntE], nE);
        baseN = atomicAdd(&counters[cntN], nN);
    }
    __syncthreads();
    for (int i = threadIdx.x; i < nE; i += blockDim.x) {
        int g = baseE + i; if (g < elistCap) elist[g] = lE[i];
    }
    for (int i = threadIdx.x; i < nN; i += blockDim.x) {
        int g = baseN + i; if (g < nodesCap) nodes[g] = lN[i];
    }
}

__global__ void k_finS1(int* slot1, const int* nodesS1, int* slot0, int* nodesS0,
                        int* counters, int* deg) {
    int k = blockIdx.x * blockDim.x + threadIdx.x;
    int cnt = counters[0]; if (cnt > MAXS1) cnt = MAXS1;
    if (k < cnt) {
        int n = nodesS1[k];
        slot1[n] = k;
        slot0[n] = -2;       // S1 subset of S0 (dst features needed for er)
        nodesS0[k] = n;
    }
    if (k < MAXS1) deg[k] = 0;
    if (k == 0) counters[1] = cnt;
}

__global__ void k_finS0(int* slot0, const int* nodesS0, const int* counters) {
    int k = blockIdx.x * blockDim.x + threadIdx.x;
    int cnt = counters[1]; if (cnt > MAXS0) cnt = MAXS0;
    if (k < cnt) slot0[nodesS0[k]] = k;
}

// --- layer-1 CSR bucketing by S1 dst -------------------------------------

__global__ void k_deg(const int* e1list, const int* counters, const int* dst,
                      const int* slot1, int* deg) {
    int i = blockIdx.x * blockDim.x + threadIdx.x;
    int stride = gridDim.x * blockDim.x;
    int cnt = counters[3]; if (cnt > MAXE1) cnt = MAXE1;
    for (; i < cnt; i += stride) {
        int e = e1list[i];
        atomicAdd(&deg[slot1[dst[e]]], 1);
    }
}

// single-block Hillis-Steele prefix scan over deg -> rowstart, cursor
#define PFXT 1024
__global__ void k_pfx(const int* counters, const int* __restrict__ deg,
                      int* rowstart, int* cursor) {
    __shared__ int buf[PFXT];
    __shared__ int carrySh;
    int t = threadIdx.x;
    int cnt = counters[0]; if (cnt > MAXS1) cnt = MAXS1;
    if (t == 0) carrySh = 0;
    __syncthreads();
    for (int base = 0; base < cnt; base += PFXT) {
        int i = base + t;
        int v = (i < cnt) ? deg[i] : 0;
        buf[t] = v;
        __syncthreads();
        for (int off = 1; off < PFXT; off <<= 1) {
            int x = (t >= off) ? buf[t - off] : 0;
            __syncthreads();
            buf[t] += x;
            __syncthreads();
        }
        int carry = carrySh;
        int excl = carry + buf[t] - v;
        if (i < cnt) { rowstart[i] = excl; cursor[i] = excl; }
        __syncthreads();
        if (t == PFXT - 1) carrySh = carry + buf[PFXT - 1];
        __syncthreads();
    }
    if (t == 0) rowstart[cnt] = carrySh;
}

__global__ void k_bucket(const int* e1list, const int* counters, const int* dst,
                         const int* slot1, int* cursor, int* ebuck) {
    int i = blockIdx.x * blockDim.x + threadIdx.x;
    int stride = gridDim.x * blockDim.x;
    int cnt = counters[3]; if (cnt > MAXE1) cnt = MAXE1;
    for (; i < cnt; i += stride) {
        int e = e1list[i];
        int kd = slot1[dst[e]];
        int pos = atomicAdd(&cursor[kd], 1);
        ebuck[pos] = e;
    }
}

// rproj[l][r][:] = rel_table[r] @ W_rel[l];  ee[l][r][h] = <rproj head h, attn_e[l][h]>
__global__ void k_rel(const float* rel_table, const float* __restrict__ W_rel,
                      const float* attn_e, float* rproj, float* ee) {
    int b = blockIdx.x;               // 0 .. 2*NR-1
    int l = b / NR, r = b % NR;
    int t = threadIdx.x;              // 0..127
    __shared__ float row[HIDD];
    __shared__ float rp[HIDD];
    row[t] = rel_table[r * HIDD + t];
    __syncthreads();
    const float* W = W_rel + l * HIDD * HIDD;
    float acc = 0.f;
    for (int j = 0; j < HIDD; j++) acc += row[j] * W[j * HIDD + t];
    rproj[(l * NR + r) * HIDD + t] = acc;
    rp[t] = acc;
    __syncthreads();
    if (t < HH) {
        float s = 0.f;
        for (int d = 0; d < DD; d++) s += rp[t * DD + d] * attn_e[(l * HH + t) * DD + d];
        ee[(l * NR + r) * HH + t] = s;
    }
}

// feat0 + el0/er0 for all S0 nodes; 8 nodes per block tile so each pass over
// W_ent (64 KB) is amortized across 8 matvecs.
#define FT 8
__global__ void k_feat0(const int* nodesS0, const int* counters, const int* ent_ids,
                        const float* __restrict__ ent_table, const float* __restrict__ W_ent,
                        const float* __restrict__ attn_l, const float* __restrict__ attn_r,
                        float* feat0, float* el0, float* er0) {
    int t = threadIdx.x;              // 0..127
    int cnt = counters[1]; if (cnt > MAXS0) cnt = MAXS0;
    __shared__ float rows[FT][HIDD];
    int nTiles = (cnt + FT - 1) / FT;
    for (int tile = blockIdx.x; tile < nTiles; tile += gridDim.x) {
        int k0 = tile * FT;
        #pragma unroll
        for (int m = 0; m < FT; m++) {
            int k = k0 + m;
            int n = nodesS0[k < cnt ? k : 0];
            rows[m][t] = ent_table[(long)ent_ids[n] * HIDD + t];
        }
        __syncthreads();
        float acc[FT];
        #pragma unroll
        for (int m = 0; m < FT; m++) acc[m] = 0.f;
        for (int j = 0; j < HIDD; j++) {
            float w = W_ent[j * HIDD + t];
            #pragma unroll
            for (int m = 0; m < FT; m++) acc[m] += rows[m][j] * w;  // LDS broadcast
        }
        __syncthreads();
        #pragma unroll
        for (int m = 0; m < FT; m++) {
            int k = k0 + m;
            if (k < cnt) feat0[k * HIDD + t] = acc[m];
            rows[m][t] = acc[m];
        }
        __syncthreads();
        // 8 nodes x 8 heads x {el,er} = 128 tasks, one per thread
        {
            int m = t >> 4, idx = t & 15, h = idx >> 1, isR = idx & 1;
            int k = k0 + m;
            if (k < cnt) {
                const float* av = (isR ? attn_r : attn_l) + h * DD;
                float s = 0.f;
                for (int d = 0; d < DD; d++) s += rows[m][h * DD + d] * av[d];
                if (isR) er0[k * HH + h] = s; else el0[k * HH + h] = s;
            }
        }
        __syncthreads();
    }
}

// Fused layer-1: one block per S1 node. Walks its CSR edge bucket keeping
// message acc + softmax denom in registers (score recomputed per 16-thread
// head group via broadcast loads -> no barriers in the edge loop), then
// normalizes and immediately projects through W_ent[1] + el1/er1.
__global__ void k_layer1(const int* counters, const int* nodesS1,
                         const int* __restrict__ rowstart, const int* __restrict__ ebuck,
                         const int* __restrict__ src, const int* __restrict__ rel_ids,
                         const int* __restrict__ slot0,
                         const float* __restrict__ feat0, const float* __restrict__ rproj0,
                         const float* __restrict__ el0, const float* __restrict__ er0,
                         const float* __restrict__ ee0,
                         const float* __restrict__ W_ent1,
                         const float* attn_l1, const float* attn_r1,
                         float* feat1, float* el1, float* er1) {
    int t = threadIdx.x;              // 0..127 (col)
    int h = t >> 4;                   // head of this col
    int cnt = counters[0]; if (cnt > MAXS1) cnt = MAXS1;
    __shared__ float row[HIDD];
    __shared__ float f[HIDD];
    for (int k = blockIdx.x; k < cnt; k += gridDim.x) {
        int n = nodesS1[k];
        int kd0 = slot0[n];
        float er_h = er0[kd0 * HH + h];
        int lo = rowstart[k], hi = rowstart[k + 1];
        float acc = 0.f, den = 0.f;
        for (int i = lo; i < hi; i++) {
            int e = ebuck[i];                 // uniform across block: broadcast
            int s = src[e];
            int ks = slot0[s];
            int rid = rel_ids[e];
            float sc = el0[ks * HH + h] + er_h + ee0[rid * HH + h];
            sc = sc >= 0.f ? sc : 0.2f * sc;
            float ex = expf(sc);              // redundant per head group, cheap
            acc += (feat0[ks * HIDD + t] + rproj0[rid * HIDD + t]) * ex;
            den += ex;                        // identical across head group
        }
        row[t] = den > 0.f ? acc / den : 0.f; // h1 row, normalized
        __syncthreads();
        float a2 = 0.f;
        for (int j = 0; j < HIDD; j++) a2 += row[j] * W_ent1[j * HIDD + t];
        feat1[k * HIDD + t] = a2;
        f[t] = a2;
        __syncthreads();
        if (t < HH) {
            float s = 0.f;
            for (int d = 0; d < DD; d++) s += f[t * DD + d] * attn_l1[t * DD + d];
            el1[k * HH + t] = s;
        } else if (t < 2 * HH) {
            int hh = t - HH;
            float s = 0.f;
            for (int d = 0; d < DD; d++) s += f[hh * DD + d] * attn_r1[hh * DD + d];
            er1[k * HH + hh] = s;
        }
        __syncthreads();
    }
}

// Fused layer-2 + CLS output: one block per graph. Batched match-scan of the
// ~1K e2list entries (coalesced filter -> LDS list), then register-resident
// score/softmax/message over the ~16 matching edges; writes out directly.
__global__ void k_layer2(const int* counters, const int* goffs,
                         const int* __restrict__ e2list,
                         const int* __restrict__ src, const int* __restrict__ dst,
                         const int* __restrict__ rel_ids,
                         const int* __restrict__ slot1, const int* __restrict__ slot2,
                         const float* __restrict__ feat1, const float* __restrict__ rproj1,
                         const float* __restrict__ el1, const float* __restrict__ er1,
                         const float* __restrict__ ee1,
                         float* out) {
    int g = blockIdx.x;               // 0..BB-1
    int t = threadIdx.x;              // 0..127
    int h = t >> 4;
    int cnt2 = counters[2]; if (cnt2 > MAXE2) cnt2 = MAXE2;
    int n = goffs[g];
    int kd1 = slot1[n];
    float er_h = er1[kd1 * HH + h];
    __shared__ int lE[128];
    __shared__ int lc;
    float acc = 0.f, den = 0.f;
    for (int base = 0; base < cnt2; base += blockDim.x) {
        if (t == 0) lc = 0;
        __syncthreads();
        int i = base + t;
        if (i < cnt2) {
            int e = e2list[i];
            if (slot2[dst[e]] == g) {
                int p = atomicAdd(&lc, 1);
                lE[p] = e;
            }
        }
        __syncthreads();
        int m = lc;
        for (int q = 0; q < m; q++) {
            int e = lE[q];                    // LDS broadcast
            int s = src[e];
            int ks = slot1[s];
            int rid = rel_ids[e];
            float sc = el1[ks * HH + h] + er_h + ee1[rid * HH + h];
            sc = sc >= 0.f ? sc : 0.2f * sc;
            float ex = expf(sc);
            acc += (feat1[ks * HIDD + t] + rproj1[rid * HIDD + t]) * ex;
            den += ex;
        }
        __syncthreads();
    }
    out[g * HIDD + t] = den > 0.f ? acc / den : 0.f;
}

extern "C" void kernel_launch(void* const* d_in, const int* in_sizes, int n_in,
                              void* d_out, int out_size, void* d_ws, size_t ws_size,
                              hipStream_t stream) {
    const float* ent_table = (const float*)d_in[0];
    const float* rel_table = (const float*)d_in[1];
    const float* W_ent     = (const float*)d_in[2];   // [2,128,128]
    const float* W_rel     = (const float*)d_in[3];   // [2,128,128]
    const float* attn_l    = (const float*)d_in[4];   // [2,8,16]
    const float* attn_r    = (const float*)d_in[5];
    const float* attn_e    = (const float*)d_in[6];
    const int*   ent_ids   = (const int*)d_in[7];
    const int*   rel_ids   = (const int*)d_in[8];
    const int*   src       = (const int*)d_in[9];
    const int*   dst       = (const int*)d_in[10];
    const int*   goffs     = (const int*)d_in[11];
    float*       out       = (float*)d_out;

    char* p = (char*)d_ws;
    auto alloc = [&](size_t nbytes) {
        void* q = (void*)p;
        p += (nbytes + 255) & ~(size_t)255;
        return q;
    };
    float* rproj   = (float*)alloc((size_t)2 * NR * HIDD * 4);
    float* ee      = (float*)alloc((size_t)2 * NR * HH * 4);
    int*   slot2   = (int*)alloc((size_t)NN * 4);
    int*   slot1   = (int*)alloc((size_t)NN * 4);
    int*   slot0   = (int*)alloc((size_t)NN * 4);
    int*   nodesS1 = (int*)alloc((size_t)MAXS1 * 4);
    int*   nodesS0 = (int*)alloc((size_t)MAXS0 * 4);
    int*   e2list  = (int*)alloc((size_t)MAXE2 * 4);
    int*   e1list  = (int*)alloc((size_t)MAXE1 * 4);
    int*   counters= (int*)alloc(8 * 4);
    int*   deg     = (int*)alloc((size_t)MAXS1 * 4);
    int*   rowstart= (int*)alloc((size_t)(MAXS1 + 1) * 4);
    int*   cursor  = (int*)alloc((size_t)MAXS1 * 4);
    int*   ebuck   = (int*)alloc((size_t)MAXE1 * 4);
    float* feat0   = (float*)alloc((size_t)MAXS0 * HIDD * 4);
    float* el0     = (float*)alloc((size_t)MAXS0 * HH * 4);
    float* er0     = (float*)alloc((size_t)MAXS0 * HH * 4);
    float* feat1   = (float*)alloc((size_t)MAXS1 * HIDD * 4);
    float* el1     = (float*)alloc((size_t)MAXS1 * HH * 4);
    float* er1     = (float*)alloc((size_t)MAXS1 * HH * 4);

    const float* rproj0 = rproj;
    const float* rproj1 = rproj + (size_t)NR * HIDD;
    const float* ee0 = ee;
    const float* ee1 = ee + (size_t)NR * HH;
    const float* W_ent0 = W_ent;
    const float* W_ent1 = W_ent + HIDD * HIDD;
    const float* attn_l0 = attn_l, *attn_l1 = attn_l + HH * DD;
    const float* attn_r0 = attn_r, *attn_r1 = attn_r + HH * DD;

    hipLaunchKernelGGL(k_init, dim3(256), dim3(256), 0, stream,
                       slot2, slot1, slot0, counters);
    hipLaunchKernelGGL(k_seed, dim3(1), dim3(64), 0, stream,
                       goffs, slot2, slot1, nodesS1, counters);
    // scan2: edges into S2 (CLS dsts); discovers S1 via slot1
    hipLaunchKernelGGL(k_scan, dim3(512), dim3(256), 0, stream,
                       src, dst, slot2, slot1, e2list, MAXE2, nodesS1, MAXS1,
                       counters, 2, 0);
    hipLaunchKernelGGL(k_finS1, dim3((MAXS1 + 255) / 256), dim3(256), 0, stream,
                       slot1, nodesS1, slot0, nodesS0, counters, deg);
    // scan1: edges into S1; discovers S0 via slot0
    hipLaunchKernelGGL(k_scan, dim3(512), dim3(256), 0, stream,
                       src, dst, slot1, slot0, e1list, MAXE1, nodesS0, MAXS0,
                       counters, 3, 1);
    hipLaunchKernelGGL(k_finS0, dim3((MAXS0 + 255) / 256), dim3(256), 0, stream,
                       slot0, nodesS0, counters);
    // layer-1 CSR by dst
    hipLaunchKernelGGL(k_deg, dim3(256), dim3(256), 0, stream,
                       e1list, counters, dst, slot1, deg);
    hipLaunchKernelGGL(k_pfx, dim3(1), dim3(PFXT), 0, stream,
                       counters, deg, rowstart, cursor);
    hipLaunchKernelGGL(k_bucket, dim3(256), dim3(256), 0, stream,
                       e1list, counters, dst, slot1, cursor, ebuck);
    hipLaunchKernelGGL(k_rel, dim3(2 * NR), dim3(HIDD), 0, stream,
                       rel_table, W_rel, attn_e, rproj, ee);
    hipLaunchKernelGGL(k_feat0, dim3(1024), dim3(HIDD), 0, stream,
                       nodesS0, counters, ent_ids, ent_table, W_ent0,
                       attn_l0, attn_r0, feat0, el0, er0);
    hipLaunchKernelGGL(k_layer1, dim3(2048), dim3(HIDD), 0, stream,
                       counters, nodesS1, rowstart, ebuck, src, rel_ids, slot0,
                       feat0, rproj0, el0, er0, ee0, W_ent1, attn_l1, attn_r1,
                       feat1, el1, er1);
    hipLaunchKernelGGL(k_layer2, dim3(BB), dim3(HIDD), 0, stream,
                       counters, goffs, e2list, src, dst, rel_ids, slot1, slot2,
                       feat1, rproj1, el1, er1, ee1, out);
}

// Round 2
// 400.885 us; speedup vs baseline: 1.1368x; 1.1368x over previous
//
#include <hip/hip_runtime.h>
#include <hip/hip_bf16.h>

// KGE graph encoder, pruned to the backward cone of the 64 CLS nodes.
// R2: block-aggregated frontier scans; 8-node-tiled feat0.
// R3: fused per-node layer kernels (no big scattered atomics).
// R4: direct fixed-stride edge bucketing inside the scans (kills k_deg/k_pfx/
// k_bucket + e1list/e2list); 3-phase latency-parallel layer kernels (parallel
// metadata gather -> parallel scores -> independent-load column accumulation);
// finS0 folded into feat0; rel+feat0 merged. 13 -> 8 launches.

#define NN   50000      // N_NODES
#define NE   800000     // N_EDGES
#define NR   500        // N_REL
#define HH   8          // heads
#define DD   16         // per-head dim
#define HIDD 128        // HID == IN
#define BB   64         // batch (CLS nodes)

#define MAXS1 16448     // cap on |S1|                (expect ~1.1K)
#define MAXS0 50000     // node set, can't exceed NN  (expect ~16K)
#define MAXD1 256       // per-node edge bucket cap (in-degree ~Poisson(16))
#define MAXD2 256       // per-graph layer-2 bucket cap

// counters: [0]=cntS1 [1]=cntS0

__global__ void k_init(int* slot2, int* slot1, int* slot0, int* c1, int* c2,
                       int* counters) {
    int i = blockIdx.x * blockDim.x + threadIdx.x;
    int stride = gridDim.x * blockDim.x;
    for (int n = i; n < NN; n += stride) { slot2[n] = -1; slot1[n] = -1; slot0[n] = -1; }
    for (int n = i; n < MAXS1; n += stride) c1[n] = 0;
    if (i < BB) c2[i] = 0;
    if (i < 8) counters[i] = 0;
}

__global__ void k_seed(const int* goffs, int* slot2, int* slot1, int* nodesS1,
                       int* counters) {
    int i = threadIdx.x;
    if (i < BB) {
        int n = goffs[i];
        slot2[n] = i;        // graph index
        slot1[n] = -2;       // member of S1, slot assigned in k_finS1
        nodesS1[i] = n;
    }
    if (i == 0) counters[0] = BB;
}

// Frontier scan: edges whose dst is in slotHit (>=0) are appended DIRECTLY to
// the dst's fixed-stride bucket (scattered atomics over ~1K counters: cheap —
// the R2 pathology was a SINGLE shared counter). Newly-discovered src nodes
// are CAS-claimed in slotNew and appended via LDS aggregation (one global
// atomic per flush).
#define NBUF 512
__global__ void k_scan(const int* __restrict__ src, const int* __restrict__ dst,
                       const int* __restrict__ slotHit, int* __restrict__ slotNew,
                       int* __restrict__ ebuck, int maxd, int* __restrict__ cursor,
                       int* nodes, int nodesCap, int* counters, int cntN) {
    __shared__ int lN[NBUF];
    __shared__ int cNsh, baseN;
    if (threadIdx.x == 0) cNsh = 0;
    __syncthreads();
    int per = (NE + gridDim.x - 1) / gridDim.x;
    int lo = blockIdx.x * per;
    int hi = lo + per; if (hi > NE) hi = NE;
    for (int base = lo; base < hi; base += blockDim.x) {
        int e = base + threadIdx.x;
        if (e < hi) {
            int d = dst[e];
            int slot = slotHit[d];
            if (slot >= 0) {
                int pos = atomicAdd(&cursor[slot], 1);
                if (pos < maxd) ebuck[slot * maxd + pos] = e;
                int s = src[e];
                int old = atomicCAS(&slotNew[s], -1, -2);
                if (old == -1) {
                    int p2 = atomicAdd(&cNsh, 1);
                    lN[p2] = s;
                }
            }
        }
        __syncthreads();
        if (cNsh >= NBUF - 256) {
            int nN = cNsh;
            if (threadIdx.x == 0) baseN = atomicAdd(&counters[cntN], nN);
            __syncthreads();
            for (int i = threadIdx.x; i < nN; i += blockDim.x) {
                int g = baseN + i; if (g < nodesCap) nodes[g] = lN[i];
            }
            __syncthreads();
            if (threadIdx.x == 0) cNsh = 0;
        }
        __syncthreads();
    }
    int nN = cNsh;
    if (threadIdx.x == 0) baseN = atomicAdd(&counters[cntN], nN);
    __syncthreads();
    for (int i = threadIdx.x; i < nN; i += blockDim.x) {
        int g = baseN + i; if (g < nodesCap) nodes[g] = lN[i];
    }
}

__global__ void k_finS1(int* slot1, const int* nodesS1, int* slot0, int* nodesS0,
                        int* counters) {
    int k = blockIdx.x * blockDim.x + threadIdx.x;
    int cnt = counters[0]; if (cnt > MAXS1) cnt = MAXS1;
    if (k < cnt) {
        int n = nodesS1[k];
        slot1[n] = k;
        slot0[n] = -2;       // S1 is the prefix of S0 => slot0 of S1 node == its slot1
        nodesS0[k] = n;
    }
    if (k == 0) counters[1] = cnt;
}

// Merged rel-projection (blocks [0,RELB)) and feat0 (remaining blocks).
// feat0 also finalizes slot0 (was k_finS0).
#define RELB 1000
#define FT 8
__global__ void k_relfeat0(const float* rel_table, const float* __restrict__ W_rel,
                           const float* attn_e, float* rproj, float* ee,
                           const int* nodesS0, const int* counters, const int* ent_ids,
                           const float* __restrict__ ent_table, const float* __restrict__ W_ent,
                           const float* __restrict__ attn_l, const float* __restrict__ attn_r,
                           float* feat0, float* el0, float* er0, int* slot0) {
    int t = threadIdx.x;              // 0..127
    __shared__ float sh[FT][HIDD];
    if (blockIdx.x < RELB) {
        // rproj[l][r][:] = rel_table[r] @ W_rel[l]; ee = head dots with attn_e
        int b = blockIdx.x;           // 0 .. 2*NR-1 (RELB == 2*NR)
        int l = b / NR, r = b % NR;
        sh[0][t] = rel_table[r * HIDD + t];
        __syncthreads();
        const float* W = W_rel + l * HIDD * HIDD;
        float acc = 0.f;
        for (int j = 0; j < HIDD; j++) acc += sh[0][j] * W[j * HIDD + t];
        rproj[(l * NR + r) * HIDD + t] = acc;
        sh[1][t] = acc;
        __syncthreads();
        if (t < HH) {
            float s = 0.f;
            #pragma unroll
            for (int d = 0; d < DD; d++) s += sh[1][t * DD + d] * attn_e[(l * HH + t) * DD + d];
            ee[(l * NR + r) * HH + t] = s;
        }
        return;
    }
    // feat0: 8 nodes per tile so each pass over W_ent (64 KB) is amortized.
    int cnt = counters[1]; if (cnt > MAXS0) cnt = MAXS0;
    int nTiles = (cnt + FT - 1) / FT;
    int gstride = gridDim.x - RELB;
    for (int tile = blockIdx.x - RELB; tile < nTiles; tile += gstride) {
        int k0 = tile * FT;
        #pragma unroll
        for (int m = 0; m < FT; m++) {
            int k = k0 + m;
            int n = nodesS0[k < cnt ? k : 0];
            if (k < cnt && t == 0) slot0[n] = k;      // finalize slot0 here
            sh[m][t] = ent_table[(long)ent_ids[n] * HIDD + t];
        }
        __syncthreads();
        float acc[FT];
        #pragma unroll
        for (int m = 0; m < FT; m++) acc[m] = 0.f;
        for (int j = 0; j < HIDD; j++) {
            float w = W_ent[j * HIDD + t];
            #pragma unroll
            for (int m = 0; m < FT; m++) acc[m] += sh[m][j] * w;  // LDS broadcast
        }
        __syncthreads();
        #pragma unroll
        for (int m = 0; m < FT; m++) {
            int k = k0 + m;
            if (k < cnt) feat0[k * HIDD + t] = acc[m];
            sh[m][t] = acc[m];
        }
        __syncthreads();
        // 8 nodes x 8 heads x {el,er} = 128 tasks, one per thread
        {
            int m = t >> 4, idx = t & 15, h = idx >> 1, isR = idx & 1;
            int k = k0 + m;
            if (k < cnt) {
                const float* av = (isR ? attn_r : attn_l) + h * DD;
                float s = 0.f;
                #pragma unroll
                for (int d = 0; d < DD; d++) s += sh[m][h * DD + d] * av[d];
                if (isR) er0[k * HH + h] = s; else el0[k * HH + h] = s;
            }
        }
        __syncthreads();
    }
}

// Fused layer-1, latency-parallel: per S1 node k (one block):
//   A) parallel metadata gather: one thread per edge resolves ks/rid -> LDS
//      (one dependent-load chain TOTAL, not one per edge)
//   B) parallel scores: one thread per (edge,head) -> exp -> LDS
//   C) column-parallel accumulation: all feat0/rproj row loads have
//      LDS-resident addresses -> independent -> memory-level parallelism
// then normalize + W_ent[1] matvec + el1/er1, all in the same block.
__global__ void k_layer1(const int* counters,
                         const int* __restrict__ c1, const int* __restrict__ ebuck1,
                         const int* __restrict__ src, const int* __restrict__ rel_ids,
                         const int* __restrict__ slot0,
                         const float* __restrict__ feat0, const float* __restrict__ rproj0,
                         const float* __restrict__ el0, const float* __restrict__ er0,
                         const float* __restrict__ ee0,
                         const float* __restrict__ W_ent1,
                         const float* attn_l1, const float* attn_r1,
                         float* feat1, float* el1, float* er1) {
    int t = threadIdx.x;              // 0..127 (col)
    int h = t >> 4;                   // head of this col
    int cnt = counters[0]; if (cnt > MAXS1) cnt = MAXS1;
    __shared__ int   eks[MAXD1];
    __shared__ int   erid[MAXD1];
    __shared__ float exsh[MAXD1 * HH];   // 8 KB
    __shared__ float row[HIDD];
    __shared__ float f[HIDD];
    for (int k = blockIdx.x; k < cnt; k += gridDim.x) {
        int deg = c1[k]; if (deg > MAXD1) deg = MAXD1;
        for (int i = t; i < deg; i += blockDim.x) {
            int e = ebuck1[k * MAXD1 + i];
            eks[i]  = slot0[src[e]];
            erid[i] = rel_ids[e];
        }
        __syncthreads();
        for (int idx = t; idx < deg * HH; idx += blockDim.x) {
            int i = idx >> 3, hh = idx & 7;
            // er0 of dst: slot0(dst) == k because S1 is the prefix of S0
            float sc = el0[eks[i] * HH + hh] + er0[k * HH + hh] + ee0[erid[i] * HH + hh];
            sc = sc >= 0.f ? sc : 0.2f * sc;
            exsh[idx] = expf(sc);
        }
        __syncthreads();
        float acc = 0.f, den = 0.f;
        #pragma unroll 4
        for (int i = 0; i < deg; i++) {
            float ex = exsh[i * HH + h];
            acc += (feat0[eks[i] * HIDD + t] + rproj0[erid[i] * HIDD + t]) * ex;
            den += ex;
        }
        row[t] = den > 0.f ? acc / den : 0.f;   // normalized h1 row
        __syncthreads();
        float a2 = 0.f;
        for (int j = 0; j < HIDD; j++) a2 += row[j] * W_ent1[j * HIDD + t];
        feat1[k * HIDD + t] = a2;
        f[t] = a2;
        __syncthreads();
        if (t < HH) {
            float s = 0.f;
            #pragma unroll
            for (int d = 0; d < DD; d++) s += f[t * DD + d] * attn_l1[t * DD + d];
            el1[k * HH + t] = s;
        } else if (t < 2 * HH) {
            int hh = t - HH;
            float s = 0.f;
            #pragma unroll
            for (int d = 0; d < DD; d++) s += f[hh * DD + d] * attn_r1[hh * DD + d];
            er1[k * HH + hh] = s;
        }
        __syncthreads();
    }
}

// Fused layer-2 + CLS output: one block per graph, direct bucket iteration
// (buckets were filled by scan2), same 3-phase structure as layer-1.
__global__ void k_layer2(const int* __restrict__ c2, const int* __restrict__ ebuck2,
                         const int* __restrict__ src, const int* __restrict__ rel_ids,
                         const int* __restrict__ slot1,
                         const float* __restrict__ feat1, const float* __restrict__ rproj1,
                         const float* __restrict__ el1, const float* __restrict__ er1,
                         const float* __restrict__ ee1,
                         float* out) {
    int g = blockIdx.x;               // 0..BB-1
    int t = threadIdx.x;              // 0..127
    int h = t >> 4;
    __shared__ int   eks[MAXD2];
    __shared__ int   erid[MAXD2];
    __shared__ float exsh[MAXD2 * HH];
    int deg = c2[g]; if (deg > MAXD2) deg = MAXD2;
    for (int i = t; i < deg; i += blockDim.x) {
        int e = ebuck2[g * MAXD2 + i];
        eks[i]  = slot1[src[e]];      // srcs of layer-2 edges are in S1
        erid[i] = rel_ids[e];
    }
    __syncthreads();
    for (int idx = t; idx < deg * HH; idx += blockDim.x) {
        int i = idx >> 3, hh = idx & 7;
        // er1 of dst: slot1(CLS of graph g) == g (seeded order)
        float sc = el1[eks[i] * HH + hh] + er1[g * HH + hh] + ee1[erid[i] * HH + hh];
        sc = sc >= 0.f ? sc : 0.2f * sc;
        exsh[idx] = expf(sc);
    }
    __syncthreads();
    float acc = 0.f, den = 0.f;
    #pragma unroll 4
    for (int i = 0; i < deg; i++) {
        float ex = exsh[i * HH + h];
        acc += (feat1[eks[i] * HIDD + t] + rproj1[erid[i] * HIDD + t]) * ex;
        den += ex;
    }
    out[g * HIDD + t] = den > 0.f ? acc / den : 0.f;
}

extern "C" void kernel_launch(void* const* d_in, const int* in_sizes, int n_in,
                              void* d_out, int out_size, void* d_ws, size_t ws_size,
                              hipStream_t stream) {
    const float* ent_table = (const float*)d_in[0];
    const float* rel_table = (const float*)d_in[1];
    const float* W_ent     = (const float*)d_in[2];   // [2,128,128]
    const float* W_rel     = (const float*)d_in[3];   // [2,128,128]
    const float* attn_l    = (const float*)d_in[4];   // [2,8,16]
    const float* attn_r    = (const float*)d_in[5];
    const float* attn_e    = (const float*)d_in[6];
    const int*   ent_ids   = (const int*)d_in[7];
    const int*   rel_ids   = (const int*)d_in[8];
    const int*   src       = (const int*)d_in[9];
    const int*   dst       = (const int*)d_in[10];
    const int*   goffs     = (const int*)d_in[11];
    float*       out       = (float*)d_out;

    char* p = (char*)d_ws;
    auto alloc = [&](size_t nbytes) {
        void* q = (void*)p;
        p += (nbytes + 255) & ~(size_t)255;
        return q;
    };
    float* rproj   = (float*)alloc((size_t)2 * NR * HIDD * 4);
    float* ee      = (float*)alloc((size_t)2 * NR * HH * 4);
    int*   slot2   = (int*)alloc((size_t)NN * 4);
    int*   slot1   = (int*)alloc((size_t)NN * 4);
    int*   slot0   = (int*)alloc((size_t)NN * 4);
    int*   nodesS1 = (int*)alloc((size_t)MAXS1 * 4);
    int*   nodesS0 = (int*)alloc((size_t)MAXS0 * 4);
    int*   counters= (int*)alloc(8 * 4);
    int*   c1      = (int*)alloc((size_t)MAXS1 * 4);
    int*   c2      = (int*)alloc((size_t)BB * 4);
    int*   ebuck1  = (int*)alloc((size_t)MAXS1 * MAXD1 * 4);
    int*   ebuck2  = (int*)alloc((size_t)BB * MAXD2 * 4);
    float* feat0   = (float*)alloc((size_t)MAXS0 * HIDD * 4);
    float* el0     = (float*)alloc((size_t)MAXS0 * HH * 4);
    float* er0     = (float*)alloc((size_t)MAXS0 * HH * 4);
    float* feat1   = (float*)alloc((size_t)MAXS1 * HIDD * 4);
    float* el1     = (float*)alloc((size_t)MAXS1 * HH * 4);
    float* er1     = (float*)alloc((size_t)MAXS1 * HH * 4);

    const float* rproj0 = rproj;
    const float* rproj1 = rproj + (size_t)NR * HIDD;
    const float* ee0 = ee;
    const float* ee1 = ee + (size_t)NR * HH;
    const float* W_ent0 = W_ent;
    const float* W_ent1 = W_ent + HIDD * HIDD;
    const float* attn_l0 = attn_l, *attn_l1 = attn_l + HH * DD;
    const float* attn_r0 = attn_r, *attn_r1 = attn_r + HH * DD;

    hipLaunchKernelGGL(k_init, dim3(256), dim3(256), 0, stream,
                       slot2, slot1, slot0, c1, c2, counters);
    hipLaunchKernelGGL(k_seed, dim3(1), dim3(64), 0, stream,
                       goffs, slot2, slot1, nodesS1, counters);
    // scan2: edges into S2 (CLS dsts) -> per-graph buckets; discovers S1
    hipLaunchKernelGGL(k_scan, dim3(512), dim3(256), 0, stream,
                       src, dst, slot2, slot1, ebuck2, MAXD2, c2,
                       nodesS1, MAXS1, counters, 0);
    hipLaunchKernelGGL(k_finS1, dim3((MAXS1 + 255) / 256), dim3(256), 0, stream,
                       slot1, nodesS1, slot0, nodesS0, counters);
    // scan1: edges into S1 -> per-node buckets; discovers S0
    hipLaunchKernelGGL(k_scan, dim3(512), dim3(256), 0, stream,
                       src, dst, slot1, slot0, ebuck1, MAXD1, c1,
                       nodesS0, MAXS0, counters, 1);
    hipLaunchKernelGGL(k_relfeat0, dim3(RELB + 1048), dim3(HIDD), 0, stream,
                       rel_table, W_rel, attn_e, rproj, ee,
                       nodesS0, counters, ent_ids, ent_table, W_ent0,
                       attn_l0, attn_r0, feat0, el0, er0, slot0);
    hipLaunchKernelGGL(k_layer1, dim3(1024), dim3(HIDD), 0, stream,
                       counters, c1, ebuck1, src, rel_ids, slot0,
                       feat0, rproj0, el0, er0, ee0, W_ent1, attn_l1, attn_r1,
                       feat1, el1, er1);
    hipLaunchKernelGGL(k_layer2, dim3(BB), dim3(HIDD), 0, stream,
                       c2, ebuck2, src, rel_ids, slot1,
                       feat1, rproj1, el1, er1, ee1, out);
}